// Round 7
// baseline (400.117 us; speedup 1.0000x reference)
//
#include <hip/hip_runtime.h>
#include <hip/hip_bf16.h>
#include <cstdint>
#include <cstddef>

#define NEG_SLOPE 0.01f

static __device__ __forceinline__ unsigned short f2bf(float f) {
    __hip_bfloat16 b = __float2bfloat16(f);   // RNE
    return *(unsigned short*)&b;
}

// ============================================================================
// Layer-1 GEMM: z1 = feature[N,128] @ W1[128,32] (bf16 out) + fp32 logits.
// ============================================================================

__global__ __launch_bounds__(128) void gemm1_kernel(
    const float* __restrict__ h, const float* __restrict__ W,
    const float* __restrict__ a, unsigned short* __restrict__ zb,
    float* __restrict__ s_src, float* __restrict__ s_dst, int N)
{
    __shared__ float Wl[128 * 32];
    int tid = threadIdx.x;
    int rowBase = blockIdx.x * 64;

    {
        const float4* W4 = (const float4*)W;
        float4* Wl4 = (float4*)Wl;
        for (int i = tid; i < 1024; i += 128) Wl4[i] = W4[i];
    }
    __syncthreads();

    int wv   = tid >> 6;
    int lane = tid & 63;
    int g    = lane >> 3;
    int l8   = lane & 7;
    int r0   = wv * 32 + g * 4;
    int col4 = l8 * 4;

    float acc[4][4];
#pragma unroll
    for (int i = 0; i < 4; i++)
#pragma unroll
        for (int c = 0; c < 4; c++) acc[i][c] = 0.f;

    const float4* h4  = (const float4*)h;
    const float4* Wl4 = (const float4*)Wl;

    size_t rowOff[4];
#pragma unroll
    for (int i = 0; i < 4; i++) {
        int r = rowBase + r0 + i;
        rowOff[i] = (size_t)((r < N) ? r : (N - 1)) * 32;
    }

#pragma unroll 2
    for (int kq = 0; kq < 32; kq++) {
        float4 w0 = Wl4[(kq * 4 + 0) * 8 + l8];
        float4 w1 = Wl4[(kq * 4 + 1) * 8 + l8];
        float4 w2 = Wl4[(kq * 4 + 2) * 8 + l8];
        float4 w3 = Wl4[(kq * 4 + 3) * 8 + l8];
#pragma unroll
        for (int i = 0; i < 4; i++) {
            float4 hv = h4[rowOff[i] + kq];
            acc[i][0] += hv.x * w0.x; acc[i][1] += hv.x * w0.y;
            acc[i][2] += hv.x * w0.z; acc[i][3] += hv.x * w0.w;
            acc[i][0] += hv.y * w1.x; acc[i][1] += hv.y * w1.y;
            acc[i][2] += hv.y * w1.z; acc[i][3] += hv.y * w1.w;
            acc[i][0] += hv.z * w2.x; acc[i][1] += hv.z * w2.y;
            acc[i][2] += hv.z * w2.z; acc[i][3] += hv.z * w2.w;
            acc[i][0] += hv.w * w3.x; acc[i][1] += hv.w * w3.y;
            acc[i][2] += hv.w * w3.z; acc[i][3] += hv.w * w3.w;
        }
    }

    float4 alo = ((const float4*)a)[l8];
    float4 ahi = ((const float4*)a)[8 + l8];
#pragma unroll
    for (int i = 0; i < 4; i++) {
        int row = rowBase + r0 + i;
        if (row < N) {
            ushort4 zv4 = make_ushort4(f2bf(acc[i][0]), f2bf(acc[i][1]),
                                       f2bf(acc[i][2]), f2bf(acc[i][3]));
            *(ushort4*)&zb[(size_t)row * 32 + col4] = zv4;
            float ps = acc[i][0] * alo.x + acc[i][1] * alo.y + acc[i][2] * alo.z + acc[i][3] * alo.w;
            float pd = acc[i][0] * ahi.x + acc[i][1] * ahi.y + acc[i][2] * ahi.z + acc[i][3] * ahi.w;
            ps += __shfl_xor(ps, 1, 64); ps += __shfl_xor(ps, 2, 64); ps += __shfl_xor(ps, 4, 64);
            pd += __shfl_xor(pd, 1, 64); pd += __shfl_xor(pd, 2, 64); pd += __shfl_xor(pd, 4, 64);
            if (l8 == 0) { s_src[row] = ps; s_dst[row] = pd; }
        }
    }
}

// ============================================================================
// R22 CSR build: global-atomic counting sort, 4 cheap full-occupancy kernels
// (replaces the 6-kernel two-level sort whose E-sweeps ran at 391 blocks =
// 1.5 blocks/CU). counts: 1.6M L2 atomics over 100K addresses; scatter:
// cursor = offsets copy, per-edge atomicAdd gives slot. Edge order within a
// node becomes arbitrary — only affects fp32 sum order (last-ulp).
// ============================================================================

__global__ __launch_bounds__(256) void zero_kernel(int* __restrict__ p, int n)
{
    int stride = gridDim.x * 256;
    for (int i = blockIdx.x * 256 + threadIdx.x; i < n; i += stride) p[i] = 0;
}

__global__ __launch_bounds__(256) void count_kernel(
    const int* __restrict__ dst, int* __restrict__ counts, int E)
{
    int stride = gridDim.x * 256;
    for (int i = blockIdx.x * 256 + threadIdx.x; i < E; i += stride)
        atomicAdd(&counts[dst[i]], 1);
}

__global__ __launch_bounds__(256) void scan1_kernel(
    const int* __restrict__ vals, int* __restrict__ incl,
    int* __restrict__ blockSums, int M)
{
    __shared__ int tmp[256];
    int tid = threadIdx.x;
    int i = blockIdx.x * 256 + tid;
    int v = (i < M) ? vals[i] : 0;
    tmp[tid] = v;
    __syncthreads();
#pragma unroll
    for (int off = 1; off < 256; off <<= 1) {
        int t = (tid >= off) ? tmp[tid - off] : 0;
        __syncthreads();
        tmp[tid] += t;
        __syncthreads();
    }
    if (i < M) incl[i] = tmp[tid];
    if (tid == 255) blockSums[blockIdx.x] = tmp[255];
}

// exclusive offsets + cursor copy; per-block prefix over blockSums folded in.
__global__ __launch_bounds__(256) void scan_offsets_kernel(
    const int* __restrict__ vals, const int* __restrict__ incl,
    const int* __restrict__ blockSums,
    int* __restrict__ offsets, int* __restrict__ cursor, int Nn, int E)
{
    __shared__ int red[256];
    int tid = threadIdx.x;
    int bid = blockIdx.x;
    int partial = 0;
    for (int j = tid; j < bid; j += 256) partial += blockSums[j];
    red[tid] = partial;
    __syncthreads();
#pragma unroll
    for (int off = 128; off > 0; off >>= 1) {
        if (tid < off) red[tid] += red[tid + off];
        __syncthreads();
    }
    int prefix = red[0];
    int i = bid * 256 + tid;
    if (i < Nn) {
        int v = incl[i] - vals[i] + prefix;   // exclusive
        offsets[i] = v;
        cursor[i]  = v;
    }
    if (i == 0) offsets[Nn] = E;
}

__global__ __launch_bounds__(256) void scatter_atomic_kernel(
    const int* __restrict__ src, const int* __restrict__ dst,
    int* __restrict__ cursor, int* __restrict__ csr_src, int E)
{
    int stride = gridDim.x * 256;
    for (int i = blockIdx.x * 256 + threadIdx.x; i < E; i += stride) {
        int d = dst[i];
        int pos = atomicAdd(&cursor[d], 1);
        csr_src[pos] = src[i];
    }
}

// ============================================================================
// Gather core (R21): no max-subtraction (softmax shift-invariance; logits
// |e| <~ 6 so exp(e) is well-conditioned in fp32). w = exp(e) computed in
// the preload (l1: before the W2-staging barrier). deg<=32 fast path with
// all gathers issued before the l-reduce; deg>32 routes to the 2-pass path.
// Produces vv4 = float4 of relu'd, normalized output for cols {4c..4c+3},
// valid on ALL 32 lanes (quarters combined via shfl_xor 8,16).
// ============================================================================

#define AGG32_PRELOAD(S_SRC, S_DST)                                           \
    int nodeC = (node < N) ? node : (N - 1);                                  \
    int beg = offsets[nodeC], end = offsets[nodeC + 1];                       \
    int deg = end - beg;                                                      \
    float sd = (S_DST)[nodeC];                                                \
    int pfx = beg + lane;                                                     \
    int s_pre = (deg <= 32 && pfx < end) ? csr_src[pfx] : 0;                  \
    float w_pre = 0.f;                                                        \
    if (deg <= 32 && pfx < end) {                                             \
        float e = (S_SRC)[s_pre] + sd;                                        \
        e = (e > 0.f) ? e : NEG_SLOPE * e;                                    \
        w_pre = __expf(e);                                                    \
    }

#define AGG32_CORE(S_SRC, S_DST, ZB)                                          \
    int q  = lane >> 3;                                                       \
    int c4 = (lane & 7) * 4;                                                  \
    unsigned cb = (unsigned)(lane & 7) * 8u;                                  \
    const char* zbc = (const char*)(ZB);                                      \
    float4 o4 = make_float4(0.f, 0.f, 0.f, 0.f);                              \
    float rden;                                                               \
    if (deg <= 32) {                                                          \
        int soff = s_pre << 6;                                                \
        int e0 = __shfl(soff, q + 0,  32);                                    \
        int e1 = __shfl(soff, q + 4,  32);                                    \
        int e2 = __shfl(soff, q + 8,  32);                                    \
        int e3 = __shfl(soff, q + 12, 32);                                    \
        uint2 g0 = *(const uint2*)(zbc + (cb + (unsigned)e0));                \
        uint2 g1 = *(const uint2*)(zbc + (cb + (unsigned)e1));                \
        uint2 g2 = *(const uint2*)(zbc + (cb + (unsigned)e2));                \
        uint2 g3 = *(const uint2*)(zbc + (cb + (unsigned)e3));                \
        int dgt = (deg > 16);                                                 \
        uint2 g4, g5, g6, g7;                                                 \
        if (dgt) {                                                            \
            int e4 = __shfl(soff, q + 16, 32);                                \
            int e5 = __shfl(soff, q + 20, 32);                                \
            int e6 = __shfl(soff, q + 24, 32);                                \
            int e7 = __shfl(soff, q + 28, 32);                                \
            g4 = *(const uint2*)(zbc + (cb + (unsigned)e4));                  \
            g5 = *(const uint2*)(zbc + (cb + (unsigned)e5));                  \
            g6 = *(const uint2*)(zbc + (cb + (unsigned)e6));                  \
            g7 = *(const uint2*)(zbc + (cb + (unsigned)e7));                  \
        }                                                                     \
        float l = w_pre;                                                      \
        _Pragma("unroll")                                                     \
        for (int off = 16; off > 0; off >>= 1) l += __shfl_xor(l, off, 32);   \
        rden = 1.f / fmaxf(l, 1e-9f);                                         \
        float w0 = __shfl(w_pre, q + 0,  32);                                 \
        float w1 = __shfl(w_pre, q + 4,  32);                                 \
        float w2 = __shfl(w_pre, q + 8,  32);                                 \
        float w3 = __shfl(w_pre, q + 12, 32);                                 \
        o4.x += w0 * __uint_as_float(g0.x << 16);                             \
        o4.y += w0 * __uint_as_float(g0.x & 0xffff0000u);                     \
        o4.z += w0 * __uint_as_float(g0.y << 16);                             \
        o4.w += w0 * __uint_as_float(g0.y & 0xffff0000u);                     \
        o4.x += w1 * __uint_as_float(g1.x << 16);                             \
        o4.y += w1 * __uint_as_float(g1.x & 0xffff0000u);                     \
        o4.z += w1 * __uint_as_float(g1.y << 16);                             \
        o4.w += w1 * __uint_as_float(g1.y & 0xffff0000u);                     \
        o4.x += w2 * __uint_as_float(g2.x << 16);                             \
        o4.y += w2 * __uint_as_float(g2.x & 0xffff0000u);                     \
        o4.z += w2 * __uint_as_float(g2.y << 16);                             \
        o4.w += w2 * __uint_as_float(g2.y & 0xffff0000u);                     \
        o4.x += w3 * __uint_as_float(g3.x << 16);                             \
        o4.y += w3 * __uint_as_float(g3.x & 0xffff0000u);                     \
        o4.z += w3 * __uint_as_float(g3.y << 16);                             \
        o4.w += w3 * __uint_as_float(g3.y & 0xffff0000u);                     \
        if (dgt) {                                                            \
            float w4 = __shfl(w_pre, q + 16, 32);                             \
            float w5 = __shfl(w_pre, q + 20, 32);                             \
            float w6 = __shfl(w_pre, q + 24, 32);                             \
            float w7 = __shfl(w_pre, q + 28, 32);                             \
            o4.x += w4 * __uint_as_float(g4.x << 16);                         \
            o4.y += w4 * __uint_as_float(g4.x & 0xffff0000u);                 \
            o4.z += w4 * __uint_as_float(g4.y << 16);                         \
            o4.w += w4 * __uint_as_float(g4.y & 0xffff0000u);                 \
            o4.x += w5 * __uint_as_float(g5.x << 16);                         \
            o4.y += w5 * __uint_as_float(g5.x & 0xffff0000u);                 \
            o4.z += w5 * __uint_as_float(g5.y << 16);                         \
            o4.w += w5 * __uint_as_float(g5.y & 0xffff0000u);                 \
            o4.x += w6 * __uint_as_float(g6.x << 16);                         \
            o4.y += w6 * __uint_as_float(g6.x & 0xffff0000u);                 \
            o4.z += w6 * __uint_as_float(g6.y << 16);                         \
            o4.w += w6 * __uint_as_float(g6.y & 0xffff0000u);                 \
            o4.x += w7 * __uint_as_float(g7.x << 16);                         \
            o4.y += w7 * __uint_as_float(g7.x & 0xffff0000u);                 \
            o4.z += w7 * __uint_as_float(g7.y << 16);                         \
            o4.w += w7 * __uint_as_float(g7.y & 0xffff0000u);                 \
        }                                                                     \
    } else {                                                                  \
        float l = 0.f;                                                        \
        for (int p = beg + lane; p < end; p += 32) {                          \
            float e = (S_SRC)[csr_src[p]] + sd;                               \
            e = (e > 0.f) ? e : NEG_SLOPE * e;                                \
            l += __expf(e);                                                   \
        }                                                                     \
        _Pragma("unroll")                                                     \
        for (int off = 16; off > 0; off >>= 1) l += __shfl_xor(l, off, 32);   \
        rden = 1.f / fmaxf(l, 1e-9f);                                         \
        for (int p = 0; p < deg; p += 4) {                                    \
            int idx = p + q;                                                  \
            int valid = (idx < deg);                                          \
            int s = csr_src[beg + (valid ? idx : deg - 1)];                   \
            float e = (S_SRC)[s] + sd;                                        \
            e = (e > 0.f) ? e : NEG_SLOPE * e;                                \
            float w = valid ? __expf(e) : 0.f;                                \
            uint2 u = *(const uint2*)(zbc + (cb + ((unsigned)s << 6)));       \
            o4.x += w * __uint_as_float(u.x << 16);                           \
            o4.y += w * __uint_as_float(u.x & 0xffff0000u);                   \
            o4.z += w * __uint_as_float(u.y << 16);                           \
            o4.w += w * __uint_as_float(u.y & 0xffff0000u);                   \
        }                                                                     \
    }                                                                         \
    o4.x += __shfl_xor(o4.x, 8, 32);                                          \
    o4.y += __shfl_xor(o4.y, 8, 32);                                          \
    o4.z += __shfl_xor(o4.z, 8, 32);                                          \
    o4.w += __shfl_xor(o4.w, 8, 32);                                          \
    o4.x += __shfl_xor(o4.x, 16, 32);                                         \
    o4.y += __shfl_xor(o4.y, 16, 32);                                         \
    o4.z += __shfl_xor(o4.z, 16, 32);                                         \
    o4.w += __shfl_xor(o4.w, 16, 32);                                         \
    float4 vv4;                                                               \
    vv4.x = fmaxf(o4.x * rden, 0.f);                                          \
    vv4.y = fmaxf(o4.y * rden, 0.f);                                          \
    vv4.z = fmaxf(o4.z * rden, 0.f);                                          \
    vv4.w = fmaxf(o4.w * rden, 0.f);

// ---- layer 1 agg, fused gemm2 epilogue (hybrid LDS matvec) ----
__global__ __launch_bounds__(256) void agg32_l1_kernel(
    const int* __restrict__ offsets, const int* __restrict__ csr_src,
    const float* __restrict__ s_src1, const float* __restrict__ s_dst1,
    const unsigned short* __restrict__ zb1,
    const float* __restrict__ W2, const float* __restrict__ a2,
    unsigned short* __restrict__ zb2,
    float* __restrict__ s_src2, float* __restrict__ s_dst2, int N)
{
    __shared__ float W2l[32 * 32];      // 4 KB (stage once per block)
    __shared__ float hl[8 * 32];        // 1 KB: per-group h row
    int tid  = threadIdx.x;
    int g    = tid >> 5;
    int lane = tid & 31;
    int node = blockIdx.x * 8 + g;

    AGG32_PRELOAD(s_src1, s_dst1)       // gather chain + exp, pre-barrier

    for (int i = tid; i < 1024; i += 256) W2l[i] = W2[i];   // then stage
    __syncthreads();

    if (node >= N) return;

    AGG32_CORE(s_src1, s_dst1, zb1)

    // stage h row: quarter-0 lanes hold the col-quad values (same-wave LDS)
    if (q == 0) *(float4*)&hl[g * 32 + c4] = vv4;
    const float4* hb4 = (const float4*)&hl[g * 32];
    float acc2 = 0.f;
#pragma unroll
    for (int c = 0; c < 8; ++c) {
        float4 hv = hb4[c];             // same-addr broadcast, conflict-free
        acc2 += hv.x * W2l[(c * 4 + 0) * 32 + lane];
        acc2 += hv.y * W2l[(c * 4 + 1) * 32 + lane];
        acc2 += hv.z * W2l[(c * 4 + 2) * 32 + lane];
        acc2 += hv.w * W2l[(c * 4 + 3) * 32 + lane];
    }

    zb2[(size_t)node * 32 + lane] = f2bf(acc2);
    float ps = acc2 * a2[lane];
    float pd = acc2 * a2[32 + lane];
#pragma unroll
    for (int off = 16; off > 0; off >>= 1) {
        ps += __shfl_xor(ps, off, 32);
        pd += __shfl_xor(pd, off, 32);
    }
    if (lane == 0) { s_src2[node] = ps; s_dst2[node] = pd; }
}

// ---- layer 2 agg, fused gemm3 epilogue: emits zs=z3 (fp32), s_dst3 ----
__global__ __launch_bounds__(256) void agg32_l2_kernel(
    const int* __restrict__ offsets, const int* __restrict__ csr_src,
    const float* __restrict__ s_src2, const float* __restrict__ s_dst2,
    const unsigned short* __restrict__ zb2,
    const float* __restrict__ W3, const float* __restrict__ a3,
    float* __restrict__ zs, float* __restrict__ s_dst3, int N)
{
    int tid  = threadIdx.x;
    int g    = tid >> 5;
    int lane = tid & 31;
    int node = blockIdx.x * 8 + g;
    if (node >= N) return;

    AGG32_PRELOAD(s_src2, s_dst2)
    AGG32_CORE(s_src2, s_dst2, zb2)

    // fused gemm3: z3 = sum over cols of h2 * W3 (lane holds col quad)
    float4 w3q = ((const float4*)W3)[lane & 7];
    float t = vv4.x * w3q.x + vv4.y * w3q.y + vv4.z * w3q.z + vv4.w * w3q.w;
    t += __shfl_xor(t, 1, 32);
    t += __shfl_xor(t, 2, 32);
    t += __shfl_xor(t, 4, 32);   // quarters are duplicates; 8-lane sum = total
    if (lane == 0) {
        zs[node] = t;
        s_dst3[node] = t * a3[1];
    }
}

// ---- layer 3: single-pass edge-parallel (no max), 4B gather, sigmoid ----
__global__ __launch_bounds__(256) void agg1_fused_kernel(
    const int* __restrict__ offsets, const int* __restrict__ csr_src,
    const float* __restrict__ zs, const float* __restrict__ a3,
    const float* __restrict__ s_dst, float* __restrict__ out, int N)
{
    int node = blockIdx.x * 8 + (threadIdx.x >> 5);
    int lane = threadIdx.x & 31;
    if (node >= N) return;

    int beg = offsets[node], end = offsets[node + 1];
    float sd = s_dst[node];
    float a30 = a3[0];

    float l = 0.f, o = 0.f;
    for (int p = beg + lane; p < end; p += 32) {
        float z = zs[csr_src[p]];
        float e = z * a30 + sd;
        e = (e > 0.f) ? e : NEG_SLOPE * e;
        float w = __expf(e);
        l += w;
        o += w * z;
    }
#pragma unroll
    for (int off = 16; off > 0; off >>= 1) {
        l += __shfl_xor(l, off, 32);
        o += __shfl_xor(o, off, 32);
    }
    if (lane == 0) {
        float v = o / fmaxf(l, 1e-9f);
        out[node] = 1.f / (1.f + __expf(-v));
    }
}

// ============================================================================

extern "C" void kernel_launch(void* const* d_in, const int* in_sizes, int n_in,
                              void* d_out, int out_size, void* d_ws, size_t ws_size,
                              hipStream_t stream)
{
    const float* feature = (const float*)d_in[0];
    const int*   src     = (const int*)d_in[1];
    const int*   dst     = (const int*)d_in[2];
    const float* W1      = (const float*)d_in[3];
    const float* a1      = (const float*)d_in[4];
    const float* W2      = (const float*)d_in[5];
    const float* a2      = (const float*)d_in[6];
    const float* W3      = (const float*)d_in[7];
    const float* a3      = (const float*)d_in[8];
    float* out = (float*)d_out;

    const int N = in_sizes[0] / 128;
    const int E = in_sizes[1];

    // ---- workspace layout ----
    char* p = (char*)d_ws;
    unsigned short* zb1 = (unsigned short*)p;  p += (size_t)N * 32 * sizeof(unsigned short);
    unsigned short* zb2 = (unsigned short*)p;  p += (size_t)N * 32 * sizeof(unsigned short);
    float* zs32    = (float*)p;  p += (size_t)N * 2 * sizeof(float);
    float* s_src1  = (float*)p;  p += (size_t)N * sizeof(float);
    float* s_dst1  = (float*)p;  p += (size_t)N * sizeof(float);
    float* s_src2  = (float*)p;  p += (size_t)N * sizeof(float);
    float* s_dst2  = (float*)p;  p += (size_t)N * sizeof(float);
    float* s_dst3  = (float*)p;  p += (size_t)N * sizeof(float);
    int*   offsets = (int*)p;    p += ((size_t)N + 1) * sizeof(int);
    int*   counts  = (int*)p;    p += ((size_t)N + 1) * sizeof(int);
    int*   incl    = (int*)p;    p += ((size_t)N + 1) * sizeof(int);
    int*   cursor  = (int*)p;    p += ((size_t)N + 1) * sizeof(int);
    int*   blockSums = (int*)p;  p += 1024 * sizeof(int);
    int*   csr_src = (int*)p;    p += (size_t)E * sizeof(int);

    const int nodeBlocks8  = (N + 7) / 8;
    const int gemmBlocks64 = (N + 63) / 64;
    const int scanBlocksN  = (N + 255) / 256;
    int edgeBlocks = (E + 255) / 256;
    if (edgeBlocks > 2048) edgeBlocks = 2048;

    // ---- build CSR: global-atomic counting sort (4 kernels) ----
    hipLaunchKernelGGL(zero_kernel, dim3(scanBlocksN), dim3(256), 0, stream,
                       counts, N);
    hipLaunchKernelGGL(count_kernel, dim3(edgeBlocks), dim3(256), 0, stream,
                       dst, counts, E);
    hipLaunchKernelGGL(scan1_kernel, dim3(scanBlocksN), dim3(256), 0, stream,
                       counts, incl, blockSums, N);
    hipLaunchKernelGGL(scan_offsets_kernel, dim3(scanBlocksN), dim3(256), 0, stream,
                       counts, incl, blockSums, offsets, cursor, N, E);
    hipLaunchKernelGGL(scatter_atomic_kernel, dim3(edgeBlocks), dim3(256), 0, stream,
                       src, dst, cursor, csr_src, E);

    // ---- layer 1: gemm1 -> z1; agg(l1) fused with gemm2 -> z2 ----
    hipLaunchKernelGGL(gemm1_kernel, dim3(gemmBlocks64), dim3(128), 0, stream,
                       feature, W1, a1, zb1, s_src1, s_dst1, N);
    hipLaunchKernelGGL(agg32_l1_kernel, dim3(nodeBlocks8), dim3(256), 0, stream,
                       offsets, csr_src, s_src1, s_dst1, zb1, W2, a2,
                       zb2, s_src2, s_dst2, N);

    // ---- layer 2: agg(l2) fused with gemm3 -> zs, s_dst3 ----
    hipLaunchKernelGGL(agg32_l2_kernel, dim3(nodeBlocks8), dim3(256), 0, stream,
                       offsets, csr_src, s_src2, s_dst2, zb2, W3, a3,
                       zs32, s_dst3, N);

    // ---- layer 3: single-pass edge-parallel agg + sigmoid ----
    hipLaunchKernelGGL(agg1_fused_kernel, dim3(nodeBlocks8), dim3(256), 0, stream,
                       offsets, csr_src, zs32, a3, s_dst3, out, N);
}

// Round 8
// 240.493 us; speedup vs baseline: 1.6637x; 1.6637x over previous
//
#include <hip/hip_runtime.h>
#include <hip/hip_bf16.h>
#include <cstdint>
#include <cstddef>

#define NEG_SLOPE 0.01f

static __device__ __forceinline__ unsigned short f2bf(float f) {
    __hip_bfloat16 b = __float2bfloat16(f);   // RNE
    return *(unsigned short*)&b;
}

// ============================================================================
// Layer-1 GEMM: z1 = feature[N,128] @ W1[128,32] (bf16 out) + fp32 logits.
// ============================================================================

__global__ __launch_bounds__(128) void gemm1_kernel(
    const float* __restrict__ h, const float* __restrict__ W,
    const float* __restrict__ a, unsigned short* __restrict__ zb,
    float* __restrict__ s_src, float* __restrict__ s_dst, int N)
{
    __shared__ float Wl[128 * 32];
    int tid = threadIdx.x;
    int rowBase = blockIdx.x * 64;

    {
        const float4* W4 = (const float4*)W;
        float4* Wl4 = (float4*)Wl;
        for (int i = tid; i < 1024; i += 128) Wl4[i] = W4[i];
    }
    __syncthreads();

    int wv   = tid >> 6;
    int lane = tid & 63;
    int g    = lane >> 3;
    int l8   = lane & 7;
    int r0   = wv * 32 + g * 4;
    int col4 = l8 * 4;

    float acc[4][4];
#pragma unroll
    for (int i = 0; i < 4; i++)
#pragma unroll
        for (int c = 0; c < 4; c++) acc[i][c] = 0.f;

    const float4* h4  = (const float4*)h;
    const float4* Wl4 = (const float4*)Wl;

    size_t rowOff[4];
#pragma unroll
    for (int i = 0; i < 4; i++) {
        int r = rowBase + r0 + i;
        rowOff[i] = (size_t)((r < N) ? r : (N - 1)) * 32;
    }

#pragma unroll 2
    for (int kq = 0; kq < 32; kq++) {
        float4 w0 = Wl4[(kq * 4 + 0) * 8 + l8];
        float4 w1 = Wl4[(kq * 4 + 1) * 8 + l8];
        float4 w2 = Wl4[(kq * 4 + 2) * 8 + l8];
        float4 w3 = Wl4[(kq * 4 + 3) * 8 + l8];
#pragma unroll
        for (int i = 0; i < 4; i++) {
            float4 hv = h4[rowOff[i] + kq];
            acc[i][0] += hv.x * w0.x; acc[i][1] += hv.x * w0.y;
            acc[i][2] += hv.x * w0.z; acc[i][3] += hv.x * w0.w;
            acc[i][0] += hv.y * w1.x; acc[i][1] += hv.y * w1.y;
            acc[i][2] += hv.y * w1.z; acc[i][3] += hv.y * w1.w;
            acc[i][0] += hv.z * w2.x; acc[i][1] += hv.z * w2.y;
            acc[i][2] += hv.z * w2.z; acc[i][3] += hv.z * w2.w;
            acc[i][0] += hv.w * w3.x; acc[i][1] += hv.w * w3.y;
            acc[i][2] += hv.w * w3.z; acc[i][3] += hv.w * w3.w;
        }
    }

    float4 alo = ((const float4*)a)[l8];
    float4 ahi = ((const float4*)a)[8 + l8];
#pragma unroll
    for (int i = 0; i < 4; i++) {
        int row = rowBase + r0 + i;
        if (row < N) {
            ushort4 zv4 = make_ushort4(f2bf(acc[i][0]), f2bf(acc[i][1]),
                                       f2bf(acc[i][2]), f2bf(acc[i][3]));
            *(ushort4*)&zb[(size_t)row * 32 + col4] = zv4;
            float ps = acc[i][0] * alo.x + acc[i][1] * alo.y + acc[i][2] * alo.z + acc[i][3] * alo.w;
            float pd = acc[i][0] * ahi.x + acc[i][1] * ahi.y + acc[i][2] * ahi.z + acc[i][3] * ahi.w;
            ps += __shfl_xor(ps, 1, 64); ps += __shfl_xor(ps, 2, 64); ps += __shfl_xor(ps, 4, 64);
            pd += __shfl_xor(pd, 1, 64); pd += __shfl_xor(pd, 2, 64); pd += __shfl_xor(pd, 4, 64);
            if (l8 == 0) { s_src[row] = ps; s_dst[row] = pd; }
        }
    }
}

// ============================================================================
// Atomic-free CSR build (R21 two-level counting sort — RESTORED; the R22
// global-atomic scatter cost 133 µs: 107 MB of write-allocate traffic from
// random 4B scatters + cursor RMW. This 6-kernel build measures ~25 µs.)
// ============================================================================

#define TILE_E 4096
#define NB_MAX 512     // supports N <= 131072

__global__ __launch_bounds__(256) void csr_hist_kernel(
    const int* __restrict__ dst, int* __restrict__ counts,
    int E, int TB, int NB)
{
    __shared__ int hist[NB_MAX];
    int tid = threadIdx.x;
    int t = blockIdx.x;
    for (int b = tid; b < NB; b += 256) hist[b] = 0;
    __syncthreads();
    int base = t * TILE_E;
    for (int i = tid; i < TILE_E; i += 256) {
        int k = base + i;
        if (k < E) atomicAdd(&hist[dst[k] >> 8], 1);
    }
    __syncthreads();
    for (int b = tid; b < NB; b += 256) counts[b * TB + t] = hist[b];
}

__global__ __launch_bounds__(256) void scan1_kernel(
    const int* __restrict__ vals, int* __restrict__ incl,
    int* __restrict__ blockSums, int M)
{
    __shared__ int tmp[256];
    int tid = threadIdx.x;
    int i = blockIdx.x * 256 + tid;
    int v = (i < M) ? vals[i] : 0;
    tmp[tid] = v;
    __syncthreads();
#pragma unroll
    for (int off = 1; off < 256; off <<= 1) {
        int t = (tid >= off) ? tmp[tid - off] : 0;
        __syncthreads();
        tmp[tid] += t;
        __syncthreads();
    }
    if (i < M) incl[i] = tmp[tid];
    if (tid == 255) blockSums[blockIdx.x] = tmp[255];
}

// scan2 folded in: each block computes its own prefix over blockSums.
__global__ __launch_bounds__(256) void scan3_kernel(
    const int* __restrict__ vals, const int* __restrict__ blockSums,
    int* __restrict__ cscan, int M, int E)
{
    __shared__ int red[256];
    int tid = threadIdx.x;
    int bid = blockIdx.x;
    int partial = 0;
    for (int j = tid; j < bid; j += 256) partial += blockSums[j];
    red[tid] = partial;
    __syncthreads();
#pragma unroll
    for (int off = 128; off > 0; off >>= 1) {
        if (tid < off) red[tid] += red[tid + off];
        __syncthreads();
    }
    int prefix = red[0];
    int i = bid * 256 + tid;
    if (i < M) cscan[i] = cscan[i] - vals[i] + prefix;
    if (i == 0) cscan[M] = E;
}

__global__ __launch_bounds__(256) void csr_scatter_kernel(
    const int* __restrict__ src, const int* __restrict__ dst,
    const int* __restrict__ cscan, int* __restrict__ ebuf,
    int E, int TB, int NB)
{
    __shared__ int baseB[NB_MAX];
    __shared__ int cur[NB_MAX];
    int tid = threadIdx.x;
    int t = blockIdx.x;
    for (int b = tid; b < NB; b += 256) {
        baseB[b] = cscan[b * TB + t];
        cur[b] = 0;
    }
    __syncthreads();
    int base = t * TILE_E;
    for (int i = tid; i < TILE_E; i += 256) {
        int k = base + i;
        if (k < E) {
            int d = dst[k], s = src[k];
            int b = d >> 8;
            int r = atomicAdd(&cur[b], 1);
            ebuf[baseB[b] + r] = (s << 8) | (d & 255);
        }
    }
}

__global__ __launch_bounds__(256) void csr_bucket_kernel(
    const int* __restrict__ ebuf, const int* __restrict__ cscan,
    int* __restrict__ csr_src, int* __restrict__ offsets,
    int N, int E, int TB)
{
    __shared__ int eb[8192];      // 32KB staging
    __shared__ int hist[256];
    __shared__ int loff[256];
    __shared__ int tmp[256];
    int tid = threadIdx.x;
    int b = blockIdx.x;

    int beg = cscan[b * TB];
    int endv = cscan[(b + 1) * TB];
    int cnt = endv - beg;
    int first = b << 8;

    hist[tid] = 0;
    __syncthreads();

    bool inLds = (cnt <= 8192);
    for (int i = tid; i < cnt; i += 256) {
        int v = ebuf[beg + i];
        if (inLds) eb[i] = v;
        atomicAdd(&hist[v & 255], 1);
    }
    __syncthreads();

    int hv = hist[tid];
    tmp[tid] = hv;
    __syncthreads();
#pragma unroll
    for (int off = 1; off < 256; off <<= 1) {
        int t = (tid >= off) ? tmp[tid - off] : 0;
        __syncthreads();
        tmp[tid] += t;
        __syncthreads();
    }
    loff[tid] = tmp[tid] - hv;
    __syncthreads();

    if (first + tid < N) offsets[first + tid] = beg + loff[tid];
    if (b == 0 && tid == 0) offsets[N] = E;

    hist[tid] = 0;
    __syncthreads();

    for (int i = tid; i < cnt; i += 256) {
        int v = inLds ? eb[i] : ebuf[beg + i];
        int d8 = v & 255;
        int r = atomicAdd(&hist[d8], 1);
        csr_src[beg + loff[d8] + r] = v >> 8;
    }
}

// ============================================================================
// Gather core (R21 math, R23 structure): no max-subtraction (shift-invariant
// softmax, |logit| <~ 6 well-conditioned in fp32); w = exp(e) computed in
// the preload. R23: TWO NODES per 32-lane group — both preload chains
// (offsets -> csr_src -> s_src, the longest exposed latency) are issued up
// front; node B's chain hides under node A's whole core.
// ============================================================================

struct NodePre {
    int beg, end, deg, s_pre;
    float sd, w_pre;
};

__device__ __forceinline__ NodePre agg_preload(
    int node, int N, int lane,
    const int* __restrict__ offsets, const int* __restrict__ csr_src,
    const float* __restrict__ s_src, const float* __restrict__ s_dst)
{
    NodePre r;
    int nodeC = (node < N) ? node : (N - 1);
    r.beg = offsets[nodeC];
    r.end = offsets[nodeC + 1];
    r.deg = r.end - r.beg;
    r.sd  = s_dst[nodeC];
    int pfx = r.beg + lane;
    bool fast = (r.deg <= 32) && (pfx < r.end);
    r.s_pre = fast ? csr_src[pfx] : 0;
    r.w_pre = 0.f;
    if (fast) {
        float e = s_src[r.s_pre] + r.sd;
        e = (e > 0.f) ? e : NEG_SLOPE * e;
        r.w_pre = __expf(e);
    }
    return r;
}

// Returns relu'd, normalized output for cols {4c..4c+3}, valid on all 32
// lanes (quarters combined via shfl_xor 8,16).
__device__ __forceinline__ float4 agg_core(
    int lane, NodePre np,
    const int* __restrict__ csr_src,
    const float* __restrict__ s_src,
    const unsigned short* __restrict__ zb)
{
    int q = lane >> 3;
    unsigned cb = (unsigned)(lane & 7) * 8u;
    const char* zbc = (const char*)zb;
    float4 o4 = make_float4(0.f, 0.f, 0.f, 0.f);
    float rden;

    if (np.deg <= 32) {
        int soff = np.s_pre << 6;
        int e0 = __shfl(soff, q + 0,  32);
        int e1 = __shfl(soff, q + 4,  32);
        int e2 = __shfl(soff, q + 8,  32);
        int e3 = __shfl(soff, q + 12, 32);
        uint2 g0 = *(const uint2*)(zbc + (cb + (unsigned)e0));
        uint2 g1 = *(const uint2*)(zbc + (cb + (unsigned)e1));
        uint2 g2 = *(const uint2*)(zbc + (cb + (unsigned)e2));
        uint2 g3 = *(const uint2*)(zbc + (cb + (unsigned)e3));
        int dgt = (np.deg > 16);
        uint2 g4, g5, g6, g7;
        if (dgt) {
            int e4 = __shfl(soff, q + 16, 32);
            int e5 = __shfl(soff, q + 20, 32);
            int e6 = __shfl(soff, q + 24, 32);
            int e7 = __shfl(soff, q + 28, 32);
            g4 = *(const uint2*)(zbc + (cb + (unsigned)e4));
            g5 = *(const uint2*)(zbc + (cb + (unsigned)e5));
            g6 = *(const uint2*)(zbc + (cb + (unsigned)e6));
            g7 = *(const uint2*)(zbc + (cb + (unsigned)e7));
        }
        float l = np.w_pre;
#pragma unroll
        for (int off = 16; off > 0; off >>= 1) l += __shfl_xor(l, off, 32);
        rden = 1.f / fmaxf(l, 1e-9f);
        float w0 = __shfl(np.w_pre, q + 0,  32);
        float w1 = __shfl(np.w_pre, q + 4,  32);
        float w2 = __shfl(np.w_pre, q + 8,  32);
        float w3 = __shfl(np.w_pre, q + 12, 32);
        o4.x += w0 * __uint_as_float(g0.x << 16);
        o4.y += w0 * __uint_as_float(g0.x & 0xffff0000u);
        o4.z += w0 * __uint_as_float(g0.y << 16);
        o4.w += w0 * __uint_as_float(g0.y & 0xffff0000u);
        o4.x += w1 * __uint_as_float(g1.x << 16);
        o4.y += w1 * __uint_as_float(g1.x & 0xffff0000u);
        o4.z += w1 * __uint_as_float(g1.y << 16);
        o4.w += w1 * __uint_as_float(g1.y & 0xffff0000u);
        o4.x += w2 * __uint_as_float(g2.x << 16);
        o4.y += w2 * __uint_as_float(g2.x & 0xffff0000u);
        o4.z += w2 * __uint_as_float(g2.y << 16);
        o4.w += w2 * __uint_as_float(g2.y & 0xffff0000u);
        o4.x += w3 * __uint_as_float(g3.x << 16);
        o4.y += w3 * __uint_as_float(g3.x & 0xffff0000u);
        o4.z += w3 * __uint_as_float(g3.y << 16);
        o4.w += w3 * __uint_as_float(g3.y & 0xffff0000u);
        if (dgt) {
            float w4 = __shfl(np.w_pre, q + 16, 32);
            float w5 = __shfl(np.w_pre, q + 20, 32);
            float w6 = __shfl(np.w_pre, q + 24, 32);
            float w7 = __shfl(np.w_pre, q + 28, 32);
            o4.x += w4 * __uint_as_float(g4.x << 16);
            o4.y += w4 * __uint_as_float(g4.x & 0xffff0000u);
            o4.z += w4 * __uint_as_float(g4.y << 16);
            o4.w += w4 * __uint_as_float(g4.y & 0xffff0000u);
            o4.x += w5 * __uint_as_float(g5.x << 16);
            o4.y += w5 * __uint_as_float(g5.x & 0xffff0000u);
            o4.z += w5 * __uint_as_float(g5.y << 16);
            o4.w += w5 * __uint_as_float(g5.y & 0xffff0000u);
            o4.x += w6 * __uint_as_float(g6.x << 16);
            o4.y += w6 * __uint_as_float(g6.x & 0xffff0000u);
            o4.z += w6 * __uint_as_float(g6.y << 16);
            o4.w += w6 * __uint_as_float(g6.y & 0xffff0000u);
            o4.x += w7 * __uint_as_float(g7.x << 16);
            o4.y += w7 * __uint_as_float(g7.x & 0xffff0000u);
            o4.z += w7 * __uint_as_float(g7.y << 16);
            o4.w += w7 * __uint_as_float(g7.y & 0xffff0000u);
        }
    } else {
        float l = 0.f;
        for (int p = np.beg + lane; p < np.end; p += 32) {
            float e = s_src[csr_src[p]] + np.sd;
            e = (e > 0.f) ? e : NEG_SLOPE * e;
            l += __expf(e);
        }
#pragma unroll
        for (int off = 16; off > 0; off >>= 1) l += __shfl_xor(l, off, 32);
        rden = 1.f / fmaxf(l, 1e-9f);
        for (int p = 0; p < np.deg; p += 4) {
            int idx = p + q;
            int valid = (idx < np.deg);
            int s = csr_src[np.beg + (valid ? idx : np.deg - 1)];
            float e = s_src[s] + np.sd;
            e = (e > 0.f) ? e : NEG_SLOPE * e;
            float w = valid ? __expf(e) : 0.f;
            uint2 u = *(const uint2*)(zbc + (cb + ((unsigned)s << 6)));
            o4.x += w * __uint_as_float(u.x << 16);
            o4.y += w * __uint_as_float(u.x & 0xffff0000u);
            o4.z += w * __uint_as_float(u.y << 16);
            o4.w += w * __uint_as_float(u.y & 0xffff0000u);
        }
    }

    o4.x += __shfl_xor(o4.x, 8, 32);
    o4.y += __shfl_xor(o4.y, 8, 32);
    o4.z += __shfl_xor(o4.z, 8, 32);
    o4.w += __shfl_xor(o4.w, 8, 32);
    o4.x += __shfl_xor(o4.x, 16, 32);
    o4.y += __shfl_xor(o4.y, 16, 32);
    o4.z += __shfl_xor(o4.z, 16, 32);
    o4.w += __shfl_xor(o4.w, 16, 32);
    float4 vv4;
    vv4.x = fmaxf(o4.x * rden, 0.f);
    vv4.y = fmaxf(o4.y * rden, 0.f);
    vv4.z = fmaxf(o4.z * rden, 0.f);
    vv4.w = fmaxf(o4.w * rden, 0.f);
    return vv4;
}

// ---- layer 1 agg, fused gemm2 epilogue; 2 nodes per group ----
__global__ __launch_bounds__(256) void agg32_l1_kernel(
    const int* __restrict__ offsets, const int* __restrict__ csr_src,
    const float* __restrict__ s_src1, const float* __restrict__ s_dst1,
    const unsigned short* __restrict__ zb1,
    const float* __restrict__ W2, const float* __restrict__ a2,
    unsigned short* __restrict__ zb2,
    float* __restrict__ s_src2, float* __restrict__ s_dst2, int N)
{
    __shared__ float W2l[32 * 32];      // 4 KB (stage once per block)
    __shared__ float hl[16 * 32];       // 2 KB: per-(group,node) h row
    int tid  = threadIdx.x;
    int g    = tid >> 5;
    int lane = tid & 31;
    int nodeA = blockIdx.x * 16 + g;
    int nodeB = nodeA + 8;

    // both preload chains issued before the staging barrier
    NodePre pA = agg_preload(nodeA, N, lane, offsets, csr_src, s_src1, s_dst1);
    NodePre pB = agg_preload(nodeB, N, lane, offsets, csr_src, s_src1, s_dst1);

    for (int i = tid; i < 1024; i += 256) W2l[i] = W2[i];
    __syncthreads();

    int c4 = (lane & 7) * 4;
    float a2lo = a2[lane];
    float a2hi = a2[32 + lane];

    // ---- node A ----
    {
        float4 vv4 = agg_core(lane, pA, csr_src, s_src1, zb1);
        if ((lane >> 3) == 0) *(float4*)&hl[g * 32 + c4] = vv4;   // same-wave
        const float4* hb4 = (const float4*)&hl[g * 32];
        float acc2 = 0.f;
#pragma unroll
        for (int c = 0; c < 8; ++c) {
            float4 hv = hb4[c];         // same-addr broadcast, conflict-free
            acc2 += hv.x * W2l[(c * 4 + 0) * 32 + lane];
            acc2 += hv.y * W2l[(c * 4 + 1) * 32 + lane];
            acc2 += hv.z * W2l[(c * 4 + 2) * 32 + lane];
            acc2 += hv.w * W2l[(c * 4 + 3) * 32 + lane];
        }
        float ps = acc2 * a2lo;
        float pd = acc2 * a2hi;
#pragma unroll
        for (int off = 16; off > 0; off >>= 1) {
            ps += __shfl_xor(ps, off, 32);
            pd += __shfl_xor(pd, off, 32);
        }
        if (nodeA < N) {
            zb2[(size_t)nodeA * 32 + lane] = f2bf(acc2);
            if (lane == 0) { s_src2[nodeA] = ps; s_dst2[nodeA] = pd; }
        }
    }

    // ---- node B ----
    {
        float4 vv4 = agg_core(lane, pB, csr_src, s_src1, zb1);
        if ((lane >> 3) == 0) *(float4*)&hl[(8 + g) * 32 + c4] = vv4;
        const float4* hb4 = (const float4*)&hl[(8 + g) * 32];
        float acc2 = 0.f;
#pragma unroll
        for (int c = 0; c < 8; ++c) {
            float4 hv = hb4[c];
            acc2 += hv.x * W2l[(c * 4 + 0) * 32 + lane];
            acc2 += hv.y * W2l[(c * 4 + 1) * 32 + lane];
            acc2 += hv.z * W2l[(c * 4 + 2) * 32 + lane];
            acc2 += hv.w * W2l[(c * 4 + 3) * 32 + lane];
        }
        float ps = acc2 * a2lo;
        float pd = acc2 * a2hi;
#pragma unroll
        for (int off = 16; off > 0; off >>= 1) {
            ps += __shfl_xor(ps, off, 32);
            pd += __shfl_xor(pd, off, 32);
        }
        if (nodeB < N) {
            zb2[(size_t)nodeB * 32 + lane] = f2bf(acc2);
            if (lane == 0) { s_src2[nodeB] = ps; s_dst2[nodeB] = pd; }
        }
    }
}

// ---- layer 2 agg, fused gemm3 epilogue; 2 nodes per group ----
__global__ __launch_bounds__(256) void agg32_l2_kernel(
    const int* __restrict__ offsets, const int* __restrict__ csr_src,
    const float* __restrict__ s_src2, const float* __restrict__ s_dst2,
    const unsigned short* __restrict__ zb2,
    const float* __restrict__ W3, const float* __restrict__ a3,
    float* __restrict__ zs, float* __restrict__ s_dst3, int N)
{
    int tid  = threadIdx.x;
    int g    = tid >> 5;
    int lane = tid & 31;
    int nodeA = blockIdx.x * 16 + g;
    int nodeB = nodeA + 8;

    NodePre pA = agg_preload(nodeA, N, lane, offsets, csr_src, s_src2, s_dst2);
    NodePre pB = agg_preload(nodeB, N, lane, offsets, csr_src, s_src2, s_dst2);

    float4 w3q = ((const float4*)W3)[lane & 7];
    float a31 = a3[1];

    {
        float4 vv4 = agg_core(lane, pA, csr_src, s_src2, zb2);
        float t = vv4.x * w3q.x + vv4.y * w3q.y + vv4.z * w3q.z + vv4.w * w3q.w;
        t += __shfl_xor(t, 1, 32);
        t += __shfl_xor(t, 2, 32);
        t += __shfl_xor(t, 4, 32);
        if (nodeA < N && lane == 0) {
            zs[nodeA] = t;
            s_dst3[nodeA] = t * a31;
        }
    }
    {
        float4 vv4 = agg_core(lane, pB, csr_src, s_src2, zb2);
        float t = vv4.x * w3q.x + vv4.y * w3q.y + vv4.z * w3q.z + vv4.w * w3q.w;
        t += __shfl_xor(t, 1, 32);
        t += __shfl_xor(t, 2, 32);
        t += __shfl_xor(t, 4, 32);
        if (nodeB < N && lane == 0) {
            zs[nodeB] = t;
            s_dst3[nodeB] = t * a31;
        }
    }
}

// ---- layer 3: single-pass edge-parallel (no max), 4B gather, sigmoid ----
__global__ __launch_bounds__(256) void agg1_fused_kernel(
    const int* __restrict__ offsets, const int* __restrict__ csr_src,
    const float* __restrict__ zs, const float* __restrict__ a3,
    const float* __restrict__ s_dst, float* __restrict__ out, int N)
{
    int node = blockIdx.x * 8 + (threadIdx.x >> 5);
    int lane = threadIdx.x & 31;
    if (node >= N) return;

    int beg = offsets[node], end = offsets[node + 1];
    float sd = s_dst[node];
    float a30 = a3[0];

    float l = 0.f, o = 0.f;
    for (int p = beg + lane; p < end; p += 32) {
        float z = zs[csr_src[p]];
        float e = z * a30 + sd;
        e = (e > 0.f) ? e : NEG_SLOPE * e;
        float w = __expf(e);
        l += w;
        o += w * z;
    }
#pragma unroll
    for (int off = 16; off > 0; off >>= 1) {
        l += __shfl_xor(l, off, 32);
        o += __shfl_xor(o, off, 32);
    }
    if (lane == 0) {
        float v = o / fmaxf(l, 1e-9f);
        out[node] = 1.f / (1.f + __expf(-v));
    }
}

// ============================================================================

extern "C" void kernel_launch(void* const* d_in, const int* in_sizes, int n_in,
                              void* d_out, int out_size, void* d_ws, size_t ws_size,
                              hipStream_t stream)
{
    const float* feature = (const float*)d_in[0];
    const int*   src     = (const int*)d_in[1];
    const int*   dst     = (const int*)d_in[2];
    const float* W1      = (const float*)d_in[3];
    const float* a1      = (const float*)d_in[4];
    const float* W2      = (const float*)d_in[5];
    const float* a2      = (const float*)d_in[6];
    const float* W3      = (const float*)d_in[7];
    const float* a3      = (const float*)d_in[8];
    float* out = (float*)d_out;

    const int N = in_sizes[0] / 128;
    const int E = in_sizes[1];

    const int TB = (E + TILE_E - 1) / TILE_E;
    const int NB = (N + 255) >> 8;
    const int M  = NB * TB;

    // ---- workspace layout ----
    char* p = (char*)d_ws;
    unsigned short* zb1 = (unsigned short*)p;  p += (size_t)N * 32 * sizeof(unsigned short);
    unsigned short* zb2 = (unsigned short*)p;  p += (size_t)N * 32 * sizeof(unsigned short);
    float* zs32    = (float*)p;  p += (size_t)N * 2 * sizeof(float);
    float* s_src1  = (float*)p;  p += (size_t)N * sizeof(float);
    float* s_dst1  = (float*)p;  p += (size_t)N * sizeof(float);
    float* s_src2  = (float*)p;  p += (size_t)N * sizeof(float);
    float* s_dst2  = (float*)p;  p += (size_t)N * sizeof(float);
    float* s_dst3  = (float*)p;  p += (size_t)N * sizeof(float);
    int*   offsets = (int*)p;    p += ((size_t)N + 1) * sizeof(int);
    int*   counts  = (int*)p;    p += ((size_t)M + 1) * sizeof(int);
    int*   cscan   = (int*)p;    p += ((size_t)M + 1) * sizeof(int);
    int*   blockSums = (int*)p;  p += 1024 * sizeof(int);
    int*   ebuf    = (int*)p;    p += (size_t)E * sizeof(int);
    int*   csr_src = (int*)p;    p += (size_t)E * sizeof(int);

    const int nodeBlocks8  = (N + 7) / 8;
    const int nodeBlocks16 = (N + 15) / 16;
    const int gemmBlocks64 = (N + 63) / 64;
    const int scanBlocksM  = (M + 255) / 256;

    // ---- build CSR: atomic-free two-level counting sort ----
    hipLaunchKernelGGL(csr_hist_kernel, dim3(TB), dim3(256), 0, stream,
                       dst, counts, E, TB, NB);
    hipLaunchKernelGGL(scan1_kernel, dim3(scanBlocksM), dim3(256), 0, stream,
                       counts, cscan, blockSums, M);
    hipLaunchKernelGGL(scan3_kernel, dim3(scanBlocksM), dim3(256), 0, stream,
                       counts, blockSums, cscan, M, E);
    hipLaunchKernelGGL(csr_scatter_kernel, dim3(TB), dim3(256), 0, stream,
                       src, dst, cscan, ebuf, E, TB, NB);
    hipLaunchKernelGGL(csr_bucket_kernel, dim3(NB), dim3(256), 0, stream,
                       ebuf, cscan, csr_src, offsets, N, E, TB);

    // ---- layer 1: gemm1 -> z1; agg(l1) fused with gemm2 -> z2 ----
    hipLaunchKernelGGL(gemm1_kernel, dim3(gemmBlocks64), dim3(128), 0, stream,
                       feature, W1, a1, zb1, s_src1, s_dst1, N);
    hipLaunchKernelGGL(agg32_l1_kernel, dim3(nodeBlocks16), dim3(256), 0, stream,
                       offsets, csr_src, s_src1, s_dst1, zb1, W2, a2,
                       zb2, s_src2, s_dst2, N);

    // ---- layer 2: agg(l2) fused with gemm3 -> zs, s_dst3 ----
    hipLaunchKernelGGL(agg32_l2_kernel, dim3(nodeBlocks16), dim3(256), 0, stream,
                       offsets, csr_src, s_src2, s_dst2, zb2, W3, a3,
                       zs32, s_dst3, N);

    // ---- layer 3: single-pass edge-parallel agg + sigmoid ----
    hipLaunchKernelGGL(agg1_fused_kernel, dim3(nodeBlocks8), dim3(256), 0, stream,
                       offsets, csr_src, zs32, a3, s_dst3, out, N);
}